// Round 1
// baseline (682.881 us; speedup 1.0000x reference)
//
#include <hip/hip_runtime.h>
#include <cstdint>

#define P2 2654435761u
#define P3 805459861u
#define HMASK 524287u

__global__ __launch_bounds__(256) void hash_enc_kernel(
    const float* __restrict__ pos, const float2* __restrict__ tbl,
    float* __restrict__ out, int n)
{
    int i = blockIdx.x * 256 + threadIdx.x;
    if (i >= n) return;
    float x = (pos[3 * i + 0] + 1.0f) * 0.5f;
    float y = (pos[3 * i + 1] + 1.0f) * 0.5f;
    float z = (pos[3 * i + 2] + 1.0f) * 0.5f;

    // int(16 * exp((ln2048-ln16)/15)**l), hand-verified against IEEE-double
    // semantics of the numpy reference. NOTE res[7]=153 (153.987) and
    // res[15]=2048 (2048.0000000000036 -> min-clamped).
    constexpr int RES[16] = {16, 22, 30, 42, 58, 80, 111, 153,
                             212, 294, 406, 561, 776, 1072, 1482, 2048};

    float4 o[8];
    float* of = reinterpret_cast<float*>(o);

    #pragma unroll
    for (int l = 0; l < 16; ++l) {
        const int rm1 = RES[l] - 1;
        const float rf = (float)rm1;
        float sx = x * rf, sy = y * rf, sz = z * rf;
        float fx = floorf(sx), fy = floorf(sy), fz = floorf(sz);
        float wx = sx - fx, wy = sy - fy, wz = sz - fz;
        int x0 = (int)fx, y0 = (int)fy, z0 = (int)fz;
        int x0c = min(max(x0, 0), rm1), x1c = min(max(x0 + 1, 0), rm1);
        int y0c = min(max(y0, 0), rm1), y1c = min(max(y0 + 1, 0), rm1);
        int z0c = min(max(z0, 0), rm1), z1c = min(max(z0 + 1, 0), rm1);
        // low 19 bits of the int64 hash == low 19 bits of the uint32 hash
        uint32_t hx0 = (uint32_t)x0c,      hx1 = (uint32_t)x1c;
        uint32_t hy0 = (uint32_t)y0c * P2, hy1 = (uint32_t)y1c * P2;
        uint32_t hz0 = (uint32_t)z0c * P3, hz1 = (uint32_t)z1c * P3;
        float2 c000 = tbl[(hx0 ^ hy0 ^ hz0) & HMASK];
        float2 c001 = tbl[(hx0 ^ hy0 ^ hz1) & HMASK];
        float2 c010 = tbl[(hx0 ^ hy1 ^ hz0) & HMASK];
        float2 c011 = tbl[(hx0 ^ hy1 ^ hz1) & HMASK];
        float2 c100 = tbl[(hx1 ^ hy0 ^ hz0) & HMASK];
        float2 c101 = tbl[(hx1 ^ hy0 ^ hz1) & HMASK];
        float2 c110 = tbl[(hx1 ^ hy1 ^ hz0) & HMASK];
        float2 c111 = tbl[(hx1 ^ hy1 ^ hz1) & HMASK];
        float ux = 1.0f - wx, uy = 1.0f - wy, uz = 1.0f - wz;
        float w00 = ux * uy, w01 = ux * wy, w10 = wx * uy, w11 = wx * wy;
        float f0, f1;
        f0  = (w00 * uz) * c000.x; f1  = (w00 * uz) * c000.y;
        f0 += (w00 * wz) * c001.x; f1 += (w00 * wz) * c001.y;
        f0 += (w01 * uz) * c010.x; f1 += (w01 * uz) * c010.y;
        f0 += (w01 * wz) * c011.x; f1 += (w01 * wz) * c011.y;
        f0 += (w10 * uz) * c100.x; f1 += (w10 * uz) * c100.y;
        f0 += (w10 * wz) * c101.x; f1 += (w10 * wz) * c101.y;
        f0 += (w11 * uz) * c110.x; f1 += (w11 * uz) * c110.y;
        f0 += (w11 * wz) * c111.x; f1 += (w11 * wz) * c111.y;
        of[2 * l]     = f0;
        of[2 * l + 1] = f1;
    }

    float4* ov = reinterpret_cast<float4*>(out + (size_t)i * 32);
    #pragma unroll
    for (int k = 0; k < 8; ++k) ov[k] = o[k];
}

extern "C" void kernel_launch(void* const* d_in, const int* in_sizes, int n_in,
                              void* d_out, int out_size, void* d_ws, size_t ws_size,
                              hipStream_t stream) {
    const float* pos = (const float*)d_in[0];
    const float2* tbl = (const float2*)d_in[1];
    float* out = (float*)d_out;
    int n = in_sizes[0] / 3;
    dim3 grid((n + 255) / 256), block(256);
    hash_enc_kernel<<<grid, block, 0, stream>>>(pos, tbl, out, n);
}

// Round 2
// 618.151 us; speedup vs baseline: 1.1047x; 1.1047x over previous
//
#include <hip/hip_runtime.h>
#include <cstdint>

#define P2 2654435761u
#define P3 805459861u
#define HMASK 524287u

// int(16 * exp((ln2048-ln16)/15)**l), hand-verified against IEEE-double
// semantics of the numpy reference. NOTE res[7]=153 (153.987) and
// res[15]=2048 (2048.0000000000036 -> min-clamped).
__constant__ int RES[16] = {16, 22, 30, 42, 58, 80, 111, 153,
                            212, 294, 406, 561, 776, 1072, 1482, 2048};

// One thread per (point, level). t = i*16 + l, point-major so the final
// float2 store is perfectly coalesced and the 8 gathers per thread are all
// independent (max MLP); 16x the waves of the per-point version (max TLP).
__global__ __launch_bounds__(256) void hash_enc_kernel(
    const float* __restrict__ pos, const float2* __restrict__ tbl,
    float2* __restrict__ out, int n)
{
    __shared__ int sres[16];
    if (threadIdx.x < 16) sres[threadIdx.x] = RES[threadIdx.x];
    __syncthreads();

    int t = blockIdx.x * 256 + threadIdx.x;
    int i = t >> 4;      // point index
    int l = t & 15;      // level index
    if (i >= n) return;

    // 16 consecutive lanes read the same 12 bytes -> L1 broadcast
    float x = (pos[3 * i + 0] + 1.0f) * 0.5f;
    float y = (pos[3 * i + 1] + 1.0f) * 0.5f;
    float z = (pos[3 * i + 2] + 1.0f) * 0.5f;

    const int rm1 = sres[l] - 1;   // lanes with same l broadcast; 2-way alias free
    const float rf = (float)rm1;

    float sx = x * rf, sy = y * rf, sz = z * rf;
    float fx = floorf(sx), fy = floorf(sy), fz = floorf(sz);
    float wx = sx - fx, wy = sy - fy, wz = sz - fz;
    int x0 = (int)fx, y0 = (int)fy, z0 = (int)fz;
    int x0c = min(max(x0, 0), rm1), x1c = min(max(x0 + 1, 0), rm1);
    int y0c = min(max(y0, 0), rm1), y1c = min(max(y0 + 1, 0), rm1);
    int z0c = min(max(z0, 0), rm1), z1c = min(max(z0 + 1, 0), rm1);

    // low 19 bits of the int64 hash == low 19 bits of the uint32 hash
    uint32_t hx0 = (uint32_t)x0c,      hx1 = (uint32_t)x1c;
    uint32_t hy0 = (uint32_t)y0c * P2, hy1 = (uint32_t)y1c * P2;
    uint32_t hz0 = (uint32_t)z0c * P3, hz1 = (uint32_t)z1c * P3;

    uint32_t i000 = (hx0 ^ hy0 ^ hz0) & HMASK;
    uint32_t i001 = (hx0 ^ hy0 ^ hz1) & HMASK;
    uint32_t i010 = (hx0 ^ hy1 ^ hz0) & HMASK;
    uint32_t i011 = (hx0 ^ hy1 ^ hz1) & HMASK;
    uint32_t i100 = (hx1 ^ hy0 ^ hz0) & HMASK;
    uint32_t i101 = (hx1 ^ hy0 ^ hz1) & HMASK;
    uint32_t i110 = (hx1 ^ hy1 ^ hz0) & HMASK;
    uint32_t i111 = (hx1 ^ hy1 ^ hz1) & HMASK;

    // all 8 loads independent -> issued back-to-back, one latency exposure
    float2 c000 = tbl[i000];
    float2 c001 = tbl[i001];
    float2 c010 = tbl[i010];
    float2 c011 = tbl[i011];
    float2 c100 = tbl[i100];
    float2 c101 = tbl[i101];
    float2 c110 = tbl[i110];
    float2 c111 = tbl[i111];

    float ux = 1.0f - wx, uy = 1.0f - wy, uz = 1.0f - wz;
    float w00 = ux * uy, w01 = ux * wy, w10 = wx * uy, w11 = wx * wy;
    float f0, f1;
    f0  = (w00 * uz) * c000.x; f1  = (w00 * uz) * c000.y;
    f0 += (w00 * wz) * c001.x; f1 += (w00 * wz) * c001.y;
    f0 += (w01 * uz) * c010.x; f1 += (w01 * uz) * c010.y;
    f0 += (w01 * wz) * c011.x; f1 += (w01 * wz) * c011.y;
    f0 += (w10 * uz) * c100.x; f1 += (w10 * uz) * c100.y;
    f0 += (w10 * wz) * c101.x; f1 += (w10 * wz) * c101.y;
    f0 += (w11 * uz) * c110.x; f1 += (w11 * uz) * c110.y;
    f0 += (w11 * wz) * c111.x; f1 += (w11 * wz) * c111.y;

    out[t] = make_float2(f0, f1);   // consecutive lanes -> contiguous 512B/wave
}

extern "C" void kernel_launch(void* const* d_in, const int* in_sizes, int n_in,
                              void* d_out, int out_size, void* d_ws, size_t ws_size,
                              hipStream_t stream) {
    const float* pos = (const float*)d_in[0];
    const float2* tbl = (const float2*)d_in[1];
    float2* out = (float2*)d_out;
    int n = in_sizes[0] / 3;
    long long total = (long long)n * 16;
    dim3 grid((unsigned)((total + 255) / 256)), block(256);
    hash_enc_kernel<<<grid, block, 0, stream>>>(pos, tbl, out, n);
}